// Round 5
// baseline (167.115 us; speedup 1.0000x reference)
//
#include <hip/hip_runtime.h>
#include <hip/hip_bf16.h>

// Problem constants (fixed by the reference)
#define NN 100000      // nodes
#define FF 128         // in features
#define DEG 16
#define OUTC 128       // out features
#define NSTRIPS 6250   // NN/16, exact

typedef __attribute__((ext_vector_type(8))) short short8;    // 8 bf16 in 4 VGPRs
typedef __attribute__((ext_vector_type(4))) float float4v;   // MFMA acc
typedef __attribute__((ext_vector_type(2))) float float2v;

__device__ __forceinline__ unsigned short f2b(float f) {
    union { float f; unsigned u; } v; v.f = f;
    unsigned r = v.u + 0x7fff + ((v.u >> 16) & 1);   // RNE
    return (unsigned short)(r >> 16);
}
__device__ __forceinline__ float b2f(unsigned bits16) {
    union { unsigned u; float f; } v; v.u = bits16 << 16; return v.f;
}

// ---- Kernel A: fused prep. Blocks [0,12500): x -> bf16 + fp8 tables.
//      Blocks [12500,12628): pack W into MFMA B-frag layout (bf16). ----
__global__ __launch_bounds__(256) void prep_xw(const float4* __restrict__ x,
                                               uint2* __restrict__ xb,
                                               unsigned* __restrict__ xf8,
                                               const float* __restrict__ w,
                                               unsigned short* __restrict__ wp) {
    int b = blockIdx.x;
    if (b < 12500) {
        int t = b * 256 + threadIdx.x;           // < 3,200,000
        float4 v = x[t];
        uint2 o;
        o.x = (unsigned)f2b(v.x) | ((unsigned)f2b(v.y) << 16);
        o.y = (unsigned)f2b(v.z) | ((unsigned)f2b(v.w) << 16);
        xb[t] = o;
        int u = __builtin_amdgcn_cvt_pk_fp8_f32(v.x, v.y, 0, false);   // bytes 0,1
        u = __builtin_amdgcn_cvt_pk_fp8_f32(v.z, v.w, u, true);        // bytes 2,3
        xf8[t] = (unsigned)u;
    } else {
        // wpack[((ct*8+kk)*64+lane)*8+j] = W[kk*32+(lane>>4)*8+j][ct*16+(lane&15)]
        int t = (b - 12500) * 256 + threadIdx.x; // < 32768
        int j = t & 7, lane = (t >> 3) & 63, kk = (t >> 9) & 7, ct = t >> 12;
        int k = kk * 32 + (lane >> 4) * 8 + j;
        int c = ct * 16 + (lane & 15);
        wp[t] = f2b(w[k * 128 + c]);
    }
}

// ---- Kernel C (fp8): gather-mean. One wave per 2 nodes; fp8 row = 128 B. ----
// Half-wave (32 lanes) reads one node's row; lane covers 4 features (1 uint).
__global__ __launch_bounds__(256) void gather_f8(const unsigned* __restrict__ xf8,
                                                 const int* __restrict__ adj,
                                                 uint2* __restrict__ hb) {
    int wv = (blockIdx.x * 256 + threadIdx.x) >> 6;  // 0..49999
    int lane = threadIdx.x & 63;
    int hsel = lane >> 5;            // 0: node0, 1: node1
    int col = lane & 31;             // uint (4-feature chunk) within row
    int node0 = wv * 2;
    float a0 = 0.f, a1 = 0.f, a2 = 0.f, a3 = 0.f;
#pragma unroll
    for (int k = 0; k < DEG; ++k) {
        // e0 = node0 + k*NN is even -> int4 load is 16B-aligned
        int4 e = *(const int4*)&adj[2 * (node0 + k * NN)];  // {dst0,src0,dst1,src1}
        int s = hsel ? e.w : e.y;
        unsigned v = xf8[(size_t)s * 32 + col];             // 128B per half-wave
        float2v lo = __builtin_amdgcn_cvt_pk_f32_fp8(v, false);
        float2v hi = __builtin_amdgcn_cvt_pk_f32_fp8(v, true);
        a0 += lo[0]; a1 += lo[1]; a2 += hi[0]; a3 += hi[1];
    }
    a0 *= (1.f / 16.f); a1 *= (1.f / 16.f); a2 *= (1.f / 16.f); a3 *= (1.f / 16.f);
    uint2 o;
    o.x = (unsigned)f2b(a0) | ((unsigned)f2b(a1) << 16);
    o.y = (unsigned)f2b(a2) | ((unsigned)f2b(a3) << 16);
    hb[(size_t)(node0 + hsel) * 32 + col] = o;              // 256B bf16 row
}

// ---- Kernel C (bf16 fallback if workspace too small): round-1 version ----
__global__ __launch_bounds__(256) void gather_k(const unsigned* __restrict__ xb,
                                                const int* __restrict__ adj,
                                                unsigned* __restrict__ hb) {
    int node = (int)((blockIdx.x * 256 + threadIdx.x) >> 6);
    int lane = threadIdx.x & 63;
    if (node >= NN) return;
    float a0 = 0.f, a1 = 0.f;
#pragma unroll
    for (int k = 0; k < DEG; ++k) {
        int s = adj[2 * (node + k * NN) + 1];
        unsigned v = xb[(size_t)s * 64 + lane];
        a0 += b2f(v & 0xffffu);
        a1 += b2f(v >> 16);
    }
    a0 *= (1.f / 16.f); a1 *= (1.f / 16.f);
    hb[(size_t)node * 64 + lane] = (unsigned)f2b(a0) | ((unsigned)f2b(a1) << 16);
}

// ---- Kernel D: out = sigmoid([x|h] @ W + b) — R1-proven structure,
//      doubled wave count (1.5 strips/wave) for tail + latency hiding. ----
#define GEMM_BLOCKS 2048
#define WAVES_PER_HALF 4096            // GEMM_BLOCKS*4/2
__global__ __launch_bounds__(256, 2) void gemm_k(const unsigned short* __restrict__ xb,
                                                 const unsigned short* __restrict__ hb,
                                                 const unsigned short* __restrict__ wp,
                                                 const float* __restrict__ bias,
                                                 float* __restrict__ out) {
    const int wv = blockIdx.x * 4 + (threadIdx.x >> 6);
    const int lane = threadIdx.x & 63;
    const int half = wv & 1;           // which 64-col half
    const int wslot = wv >> 1;

    short8 bfrag[4][8];
    const short8* wpv = (const short8*)wp;
#pragma unroll
    for (int j = 0; j < 4; ++j) {
        int ct = half * 4 + j;
#pragma unroll
        for (int kk = 0; kk < 8; ++kk)
            bfrag[j][kk] = wpv[(ct * 8 + kk) * 64 + lane];
    }
    float bval[4];
#pragma unroll
    for (int j = 0; j < 4; ++j)
        bval[j] = bias[(half * 4 + j) * 16 + (lane & 15)];

    const int arow = lane & 15;
    const int kg = lane >> 4;

    for (int s = wslot; s < NSTRIPS; s += WAVES_PER_HALF) {
        int node = s * 16 + arow;
        const short8* xrow = (const short8*)(xb + (size_t)node * 128) + kg;
        const short8* hrow = (const short8*)(hb + (size_t)node * 128) + kg;

        float4v acc[4];
#pragma unroll
        for (int j = 0; j < 4; ++j) acc[j] = (float4v){0.f, 0.f, 0.f, 0.f};

#pragma unroll
        for (int kk = 0; kk < 8; ++kk) {
            short8 afrag = (kk < 4) ? xrow[kk * 4] : hrow[(kk - 4) * 4];
#pragma unroll
            for (int j = 0; j < 4; ++j)
                acc[j] = __builtin_amdgcn_mfma_f32_16x16x32_bf16(afrag, bfrag[j][kk], acc[j], 0, 0, 0);
        }
        // Epilogue: D col = lane&15, row = (lane>>4)*4 + r  [verified mapping]
#pragma unroll
        for (int j = 0; j < 4; ++j) {
            int col = (half * 4 + j) * 16 + (lane & 15);
#pragma unroll
            for (int r = 0; r < 4; ++r) {
                float v = acc[j][r] + bval[j];
                v = 1.f / (1.f + __expf(-v));
                out[(size_t)(s * 16 + kg * 4 + r) * 128 + col] = v;
            }
        }
    }
}

extern "C" void kernel_launch(void* const* d_in, const int* in_sizes, int n_in,
                              void* d_out, int out_size, void* d_ws, size_t ws_size,
                              hipStream_t stream) {
    const float* x    = (const float*)d_in[0];   // [N,128]
    const int*   adj  = (const int*)d_in[1];     // [E,2] (dst,src) int32
    const float* w    = (const float*)d_in[3];   // [256,128]
    const float* bias = (const float*)d_in[4];   // [128]
    float* out = (float*)d_out;

    // Workspace layout:
    //   xb:  N*128 bf16 = 25,600,000 B @ 0
    //   hb:  N*128 bf16 = 25,600,000 B @ 25,600,000
    //   wp:  32768 bf16 =     65,536 B @ 51,200,000
    //   xf8: N*128 fp8  = 12,800,000 B @ 51,265,536   (total 64,065,536)
    unsigned short* xb = (unsigned short*)d_ws;
    unsigned short* hb = (unsigned short*)((char*)d_ws + 25600000);
    unsigned short* wp = (unsigned short*)((char*)d_ws + 51200000);
    unsigned* xf8 = (unsigned*)((char*)d_ws + 51265536);

    const bool use_f8 = ws_size >= 64065536;   // ws_size constant across calls

    prep_xw<<<12628, 256, 0, stream>>>((const float4*)x, (uint2*)xb, xf8, w, wp);
    if (use_f8)
        gather_f8<<<12500, 256, 0, stream>>>(xf8, adj, (uint2*)hb);
    else
        gather_k<<<25000, 256, 0, stream>>>((const unsigned*)xb, adj, (unsigned*)hb);
    gemm_k<<<GEMM_BLOCKS, 256, 0, stream>>>(xb, hb, wp, bias, out);
}

// Round 6
// 163.287 us; speedup vs baseline: 1.0234x; 1.0234x over previous
//
#include <hip/hip_runtime.h>
#include <hip/hip_bf16.h>

// Problem constants (fixed by the reference)
#define NN 100000      // nodes
#define FF 128         // in features
#define DEG 16
#define OUTC 128       // out features
#define NSTRIPS 6250   // NN/16, exact

typedef __attribute__((ext_vector_type(8))) short short8;    // 8 bf16 in 4 VGPRs
typedef __attribute__((ext_vector_type(4))) float float4v;   // MFMA acc
typedef __attribute__((ext_vector_type(2))) float float2v;

__device__ __forceinline__ unsigned short f2b(float f) {
    union { float f; unsigned u; } v; v.f = f;
    unsigned r = v.u + 0x7fff + ((v.u >> 16) & 1);   // RNE
    return (unsigned short)(r >> 16);
}
__device__ __forceinline__ float b2f(unsigned bits16) {
    union { unsigned u; float f; } v; v.u = bits16 << 16; return v.f;
}

// ---- Kernel A: fused prep. Blocks [0,12500): x -> bf16 + fp8 tables.
//      Blocks [12500,12628): pack W into MFMA B-frag layout (bf16). ----
__global__ __launch_bounds__(256) void prep_xw(const float4* __restrict__ x,
                                               uint2* __restrict__ xb,
                                               unsigned* __restrict__ xf8,
                                               const float* __restrict__ w,
                                               unsigned short* __restrict__ wp) {
    int b = blockIdx.x;
    if (b < 12500) {
        int t = b * 256 + threadIdx.x;           // < 3,200,000
        float4 v = x[t];
        uint2 o;
        o.x = (unsigned)f2b(v.x) | ((unsigned)f2b(v.y) << 16);
        o.y = (unsigned)f2b(v.z) | ((unsigned)f2b(v.w) << 16);
        xb[t] = o;
        int u = __builtin_amdgcn_cvt_pk_fp8_f32(v.x, v.y, 0, false);   // bytes 0,1
        u = __builtin_amdgcn_cvt_pk_fp8_f32(v.z, v.w, u, true);        // bytes 2,3
        xf8[t] = (unsigned)u;
    } else {
        // wpack[((ct*8+kk)*64+lane)*8+j] = W[kk*32+(lane>>4)*8+j][ct*16+(lane&15)]
        int t = (b - 12500) * 256 + threadIdx.x; // < 32768
        int j = t & 7, lane = (t >> 3) & 63, kk = (t >> 9) & 7, ct = t >> 12;
        int k = kk * 32 + (lane >> 4) * 8 + j;
        int c = ct * 16 + (lane & 15);
        wp[t] = f2b(w[k * 128 + c]);
    }
}

// ---- Kernel C (fp8): gather-mean. One wave per 2 nodes; fp8 row = 128 B. ----
// Half-wave (32 lanes) reads one node's row; lane covers 4 features (1 uint).
__global__ __launch_bounds__(256) void gather_f8(const unsigned* __restrict__ xf8,
                                                 const int* __restrict__ adj,
                                                 uint2* __restrict__ hb) {
    int wv = (blockIdx.x * 256 + threadIdx.x) >> 6;  // 0..49999
    int lane = threadIdx.x & 63;
    int hsel = lane >> 5;            // 0: node0, 1: node1
    int col = lane & 31;             // uint (4-feature chunk) within row
    int node0 = wv * 2;
    float a0 = 0.f, a1 = 0.f, a2 = 0.f, a3 = 0.f;
#pragma unroll
    for (int k = 0; k < DEG; ++k) {
        // e0 = node0 + k*NN is even -> int4 load is 16B-aligned
        int4 e = *(const int4*)&adj[2 * (node0 + k * NN)];  // {dst0,src0,dst1,src1}
        int s = hsel ? e.w : e.y;
        unsigned v = xf8[(size_t)s * 32 + col];             // 128B per half-wave
        float2v lo = __builtin_amdgcn_cvt_pk_f32_fp8(v, false);
        float2v hi = __builtin_amdgcn_cvt_pk_f32_fp8(v, true);
        a0 += lo[0]; a1 += lo[1]; a2 += hi[0]; a3 += hi[1];
    }
    a0 *= (1.f / 16.f); a1 *= (1.f / 16.f); a2 *= (1.f / 16.f); a3 *= (1.f / 16.f);
    uint2 o;
    o.x = (unsigned)f2b(a0) | ((unsigned)f2b(a1) << 16);
    o.y = (unsigned)f2b(a2) | ((unsigned)f2b(a3) << 16);
    hb[(size_t)(node0 + hsel) * 32 + col] = o;              // 256B bf16 row
}

// ---- Kernel C (bf16 fallback if workspace too small): round-1 version ----
__global__ __launch_bounds__(256) void gather_k(const unsigned* __restrict__ xb,
                                                const int* __restrict__ adj,
                                                unsigned* __restrict__ hb) {
    int node = (int)((blockIdx.x * 256 + threadIdx.x) >> 6);
    int lane = threadIdx.x & 63;
    if (node >= NN) return;
    float a0 = 0.f, a1 = 0.f;
#pragma unroll
    for (int k = 0; k < DEG; ++k) {
        int s = adj[2 * (node + k * NN) + 1];
        unsigned v = xb[(size_t)s * 64 + lane];
        a0 += b2f(v & 0xffffu);
        a1 += b2f(v >> 16);
    }
    a0 *= (1.f / 16.f); a1 *= (1.f / 16.f);
    hb[(size_t)node * 64 + lane] = (unsigned)f2b(a0) | ((unsigned)f2b(a1) << 16);
}

// ---- Kernel D: out = sigmoid([x|h] @ W + b) — R1/R4-proven version.
//      1024 blocks: 3 strips/wave amortizes the 32KB/wave B-frag prologue;
//      2048 blocks measured WORSE (R5: doubled B-prologue L2 traffic). ----
#define GEMM_BLOCKS 1024
#define WAVES_PER_HALF 2048            // GEMM_BLOCKS*4/2
__global__ __launch_bounds__(256, 2) void gemm_k(const unsigned short* __restrict__ xb,
                                                 const unsigned short* __restrict__ hb,
                                                 const unsigned short* __restrict__ wp,
                                                 const float* __restrict__ bias,
                                                 float* __restrict__ out) {
    const int wv = blockIdx.x * 4 + (threadIdx.x >> 6);
    const int lane = threadIdx.x & 63;
    const int half = wv & 1;           // which 64-col half
    const int wslot = wv >> 1;

    short8 bfrag[4][8];
    const short8* wpv = (const short8*)wp;
#pragma unroll
    for (int j = 0; j < 4; ++j) {
        int ct = half * 4 + j;
#pragma unroll
        for (int kk = 0; kk < 8; ++kk)
            bfrag[j][kk] = wpv[(ct * 8 + kk) * 64 + lane];
    }
    float bval[4];
#pragma unroll
    for (int j = 0; j < 4; ++j)
        bval[j] = bias[(half * 4 + j) * 16 + (lane & 15)];

    const int arow = lane & 15;
    const int kg = lane >> 4;

    for (int s = wslot; s < NSTRIPS; s += WAVES_PER_HALF) {
        int node = s * 16 + arow;
        const short8* xrow = (const short8*)(xb + (size_t)node * 128) + kg;
        const short8* hrow = (const short8*)(hb + (size_t)node * 128) + kg;

        float4v acc[4];
#pragma unroll
        for (int j = 0; j < 4; ++j) acc[j] = (float4v){0.f, 0.f, 0.f, 0.f};

#pragma unroll
        for (int kk = 0; kk < 8; ++kk) {
            short8 afrag = (kk < 4) ? xrow[kk * 4] : hrow[(kk - 4) * 4];
#pragma unroll
            for (int j = 0; j < 4; ++j)
                acc[j] = __builtin_amdgcn_mfma_f32_16x16x32_bf16(afrag, bfrag[j][kk], acc[j], 0, 0, 0);
        }
        // Epilogue: D col = lane&15, row = (lane>>4)*4 + r  [verified mapping]
#pragma unroll
        for (int j = 0; j < 4; ++j) {
            int col = (half * 4 + j) * 16 + (lane & 15);
#pragma unroll
            for (int r = 0; r < 4; ++r) {
                float v = acc[j][r] + bval[j];
                v = 1.f / (1.f + __expf(-v));
                out[(size_t)(s * 16 + kg * 4 + r) * 128 + col] = v;
            }
        }
    }
}

extern "C" void kernel_launch(void* const* d_in, const int* in_sizes, int n_in,
                              void* d_out, int out_size, void* d_ws, size_t ws_size,
                              hipStream_t stream) {
    const float* x    = (const float*)d_in[0];   // [N,128]
    const int*   adj  = (const int*)d_in[1];     // [E,2] (dst,src) int32
    const float* w    = (const float*)d_in[3];   // [256,128]
    const float* bias = (const float*)d_in[4];   // [128]
    float* out = (float*)d_out;

    // Workspace layout:
    //   xb:  N*128 bf16 = 25,600,000 B @ 0
    //   hb:  N*128 bf16 = 25,600,000 B @ 25,600,000
    //   wp:  32768 bf16 =     65,536 B @ 51,200,000
    //   xf8: N*128 fp8  = 12,800,000 B @ 51,265,536   (total 64,065,536)
    unsigned short* xb = (unsigned short*)d_ws;
    unsigned short* hb = (unsigned short*)((char*)d_ws + 25600000);
    unsigned short* wp = (unsigned short*)((char*)d_ws + 51200000);
    unsigned* xf8 = (unsigned*)((char*)d_ws + 51265536);

    const bool use_f8 = ws_size >= 64065536;   // ws_size constant across calls

    prep_xw<<<12628, 256, 0, stream>>>((const float4*)x, (uint2*)xb, xf8, w, wp);
    if (use_f8)
        gather_f8<<<12500, 256, 0, stream>>>(xf8, adj, (uint2*)hb);
    else
        gather_k<<<25000, 256, 0, stream>>>((const unsigned*)xb, adj, (unsigned*)hb);
    gemm_k<<<GEMM_BLOCKS, 256, 0, stream>>>(xb, hb, wp, bias, out);
}